// Round 1
// baseline (15640.254 us; speedup 1.0000x reference)
//
#include <hip/hip_runtime.h>

// Problem constants (fixed by reference)
#define N_TOKENS  65536
#define CODE_DIM  768
#define NUM_CODES 4096

// Tiling for the argmin GEMM
#define MT 64        // tokens per workgroup
#define KT 128       // codes per workgroup K-tile
#define DT 32        // D-chunk staged in LDS
#define LDSTRIDE 36  // padded row stride (floats): keeps ds_read_b128 conflicts <= 2-way

// ws layout (floats): [0,65536) x2 | [65536,69632) c2 | [69632,+65536) idx (int)
// requires ws_size >= 540 KB

// ---------------------------------------------------------------- kernel 0
// Row squared-norms for x (rows 0..N_TOKENS-1) and codebook (rows after).
// One 64-lane wave per row, 3x float4 per lane, shuffle reduction.
__global__ __launch_bounds__(256) void vq_norms_kernel(
    const float* __restrict__ x, const float* __restrict__ cb,
    float* __restrict__ x2, float* __restrict__ c2) {
  const int wave = threadIdx.x >> 6;
  const int lane = threadIdx.x & 63;
  const int row  = blockIdx.x * 4 + wave;
  const float* src;
  float* dst;
  if (row < N_TOKENS) {
    src = x + (size_t)row * CODE_DIM;
    dst = x2 + row;
  } else {
    const int r = row - N_TOKENS;
    if (r >= NUM_CODES) return;
    src = cb + (size_t)r * CODE_DIM;
    dst = c2 + r;
  }
  const float4* s4 = (const float4*)src;
  float acc = 0.f;
#pragma unroll
  for (int i = 0; i < 3; ++i) {
    float4 v = s4[lane + 64 * i];
    acc += (v.x * v.x + v.y * v.y) + (v.z * v.z + v.w * v.w);
  }
#pragma unroll
  for (int off = 32; off > 0; off >>= 1) acc += __shfl_down(acc, off, 64);
  if (lane == 0) *dst = acc;
}

// ---------------------------------------------------------------- kernel 1
// Tiled fp32 distance + running argmin.
// 256 threads: tx = tid&15 (codes), ty = tid>>4 (tokens).
// Thread register tile: 4 tokens (m = ty + 16*i) x 8 codes (k = tx + 16*j).
// dist replicates np: (x2 + c2) - 2*dot, ascending-k strict-< tie-break.
__global__ __launch_bounds__(256) void vq_argmin_kernel(
    const float* __restrict__ x, const float* __restrict__ cb,
    const float* __restrict__ x2, const float* __restrict__ c2,
    int* __restrict__ out_idx) {
  __shared__ float xs[MT * LDSTRIDE];   // 9216 B (reused as reduction vals)
  __shared__ float cs[KT * LDSTRIDE];   // 18432 B (reused as reduction idxs)
  __shared__ float x2s[MT];
  __shared__ float c2s[KT];

  const int tid = threadIdx.x;
  const int tx = tid & 15;
  const int ty = tid >> 4;
  const int tokBase = blockIdx.x * MT;

  if (tid < MT) x2s[tid] = x2[tokBase + tid];

  float bestv[4];
  int   besti[4];
#pragma unroll
  for (int i = 0; i < 4; ++i) { bestv[i] = 3.4e38f; besti[i] = 0; }

  const float4* xg = (const float4*)x;
  const float4* cg = (const float4*)cb;

  for (int kt = 0; kt < NUM_CODES / KT; ++kt) {
    const int kBase = kt * KT;
    __syncthreads();  // prior epilogue reads of c2s done before overwrite
    if (tid < KT) c2s[tid] = c2[kBase + tid];

    float acc[4][8];
#pragma unroll
    for (int i = 0; i < 4; ++i)
#pragma unroll
      for (int j = 0; j < 8; ++j) acc[i][j] = 0.f;

    for (int dc = 0; dc < CODE_DIM / DT; ++dc) {
      __syncthreads();  // prior compute reads of xs/cs done before restage
      // stage x tile: 64 rows x 32 cols = 512 float4, 2 per thread
#pragma unroll
      for (int r = 0; r < 2; ++r) {
        int f = tid + 256 * r;
        int row = f >> 3, c4 = f & 7;
        float4 v = xg[(size_t)(tokBase + row) * (CODE_DIM / 4) + dc * 8 + c4];
        *(float4*)&xs[row * LDSTRIDE + c4 * 4] = v;
      }
      // stage c tile: 128 rows x 32 cols = 1024 float4, 4 per thread
#pragma unroll
      for (int r = 0; r < 4; ++r) {
        int f = tid + 256 * r;
        int row = f >> 3, c4 = f & 7;
        float4 v = cg[(size_t)(kBase + row) * (CODE_DIM / 4) + dc * 8 + c4];
        *(float4*)&cs[row * LDSTRIDE + c4 * 4] = v;
      }
      __syncthreads();

#pragma unroll
      for (int dd = 0; dd < DT / 4; ++dd) {
        float4 xv[4], cv[8];
#pragma unroll
        for (int i = 0; i < 4; ++i)
          xv[i] = *(const float4*)&xs[(ty + 16 * i) * LDSTRIDE + dd * 4];
#pragma unroll
        for (int j = 0; j < 8; ++j)
          cv[j] = *(const float4*)&cs[(tx + 16 * j) * LDSTRIDE + dd * 4];
#pragma unroll
        for (int i = 0; i < 4; ++i)
#pragma unroll
          for (int j = 0; j < 8; ++j)
            acc[i][j] += (xv[i].x * cv[j].x + xv[i].y * cv[j].y) +
                         (xv[i].z * cv[j].z + xv[i].w * cv[j].w);
      }
    }

    // epilogue: dist = (x2 + c2) - 2*dot; ascending k within thread
#pragma unroll
    for (int i = 0; i < 4; ++i) {
      const float xx = x2s[ty + 16 * i];
#pragma unroll
      for (int j = 0; j < 8; ++j) {
        float dist = (xx + c2s[tx + 16 * j]) - 2.0f * acc[i][j];
        int k = kBase + tx + 16 * j;
        if (dist < bestv[i]) { bestv[i] = dist; besti[i] = k; }
      }
    }
  }

  // cross-tx reduction through LDS (reuse xs for vals, cs for idxs)
  __syncthreads();
  float* redv = xs;          // 64*16 = 1024 floats
  int*   redi = (int*)cs;    // 64*16 = 1024 ints
#pragma unroll
  for (int i = 0; i < 4; ++i) {
    const int m = ty + 16 * i;
    redv[m * 16 + tx] = bestv[i];
    redi[m * 16 + tx] = besti[i];
  }
  __syncthreads();
  if (tid < MT) {
    float bv = redv[tid * 16];
    int   bi = redi[tid * 16];
#pragma unroll
    for (int t = 1; t < 16; ++t) {
      float v = redv[tid * 16 + t];
      int   k = redi[tid * 16 + t];
      if (v < bv || (v == bv && k < bi)) { bv = v; bi = k; }
    }
    out_idx[tokBase + tid] = bi;
  }
}

// ---------------------------------------------------------------- kernel 2
// Gather codebook rows into d_out[0:N*D] and write indices (as float) after.
__global__ __launch_bounds__(256) void vq_gather_kernel(
    const float* __restrict__ cb, const int* __restrict__ idx,
    float* __restrict__ out) {
  const int wave = threadIdx.x >> 6;
  const int lane = threadIdx.x & 63;
  const int token = blockIdx.x * 4 + wave;
  const int k = idx[token];
  const float4* src = (const float4*)(cb + (size_t)k * CODE_DIM);
  float4* dst = (float4*)(out + (size_t)token * CODE_DIM);
#pragma unroll
  for (int i = 0; i < 3; ++i) dst[lane + 64 * i] = src[lane + 64 * i];
  if (lane == 0) out[(size_t)N_TOKENS * CODE_DIM + token] = (float)k;
}

// ---------------------------------------------------------------- launch
extern "C" void kernel_launch(void* const* d_in, const int* in_sizes, int n_in,
                              void* d_out, int out_size, void* d_ws, size_t ws_size,
                              hipStream_t stream) {
  const float* x  = (const float*)d_in[0];
  const float* cb = (const float*)d_in[1];
  float* out = (float*)d_out;

  float* x2  = (float*)d_ws;
  float* c2  = x2 + N_TOKENS;
  int*   idx = (int*)(c2 + NUM_CODES);

  // kernel 0: norms (one wave per row, x rows then codebook rows)
  {
    int rows = N_TOKENS + NUM_CODES;
    int grid = (rows + 3) / 4;
    vq_norms_kernel<<<grid, 256, 0, stream>>>(x, cb, x2, c2);
  }
  // kernel 1: argmin
  {
    int grid = N_TOKENS / MT;  // 1024
    vq_argmin_kernel<<<grid, 256, 0, stream>>>(x, cb, x2, c2, idx);
  }
  // kernel 2: gather + index write
  {
    int grid = N_TOKENS / 4;  // 16384
    vq_gather_kernel<<<grid, 256, 0, stream>>>(cb, idx, out);
  }
}

// Round 2
// 2081.278 us; speedup vs baseline: 7.5147x; 7.5147x over previous
//
#include <hip/hip_runtime.h>

// Problem constants (fixed by reference)
#define N_TOKENS  65536
#define CODE_DIM  768
#define NUM_CODES 4096

#define MARGIN 0.05f
#define FLTMAX 3.4028235e38f

typedef __attribute__((ext_vector_type(8))) short bf16x8;
typedef __attribute__((ext_vector_type(4))) float f32x4;

// ---------------------------------------------------------------- helpers
__device__ __forceinline__ unsigned short f2bf(float f) {
  unsigned int u = __float_as_uint(f);
  unsigned int r = (u + 0x7fffu + ((u >> 16) & 1u)) >> 16;  // RN-even
  return (unsigned short)r;
}
__device__ __forceinline__ float bf2f(unsigned short h) {
  return __uint_as_float(((unsigned int)h) << 16);
}
__device__ __forceinline__ void gl2lds16(const void* g, void* l) {
  __builtin_amdgcn_global_load_lds(
      (const __attribute__((address_space(1))) unsigned int*)g,
      (__attribute__((address_space(3))) unsigned int*)l, 16, 0, 0);
}

// ---------------------------------------------------------------- convert
// One wave per row: split fp32 -> (hi, lo) bf16 and compute squared norm.
__global__ __launch_bounds__(256) void vq_convert_kernel(
    const float* __restrict__ x, const float* __restrict__ cb,
    unsigned short* __restrict__ xh, unsigned short* __restrict__ xl,
    unsigned short* __restrict__ cbh, unsigned short* __restrict__ cbl,
    float* __restrict__ x2, float* __restrict__ c2, int* __restrict__ fcnt) {
  if (blockIdx.x == 0 && threadIdx.x == 0) *fcnt = 0;
  const int wave = threadIdx.x >> 6;
  const int lane = threadIdx.x & 63;
  const int row  = blockIdx.x * 4 + wave;
  const float* src;
  unsigned short *hdst, *ldst;
  float* ndst;
  if (row < N_TOKENS) {
    src = x + (size_t)row * CODE_DIM;
    hdst = xh + (size_t)row * CODE_DIM;
    ldst = xl + (size_t)row * CODE_DIM;
    ndst = x2 + row;
  } else {
    const int r = row - N_TOKENS;
    if (r >= NUM_CODES) return;
    src = cb + (size_t)r * CODE_DIM;
    hdst = cbh + (size_t)r * CODE_DIM;
    ldst = cbl + (size_t)r * CODE_DIM;
    ndst = c2 + r;
  }
  const float4* s4 = (const float4*)src;
  ushort4* h4 = (ushort4*)hdst;
  ushort4* l4 = (ushort4*)ldst;
  float acc = 0.f;
#pragma unroll
  for (int i = 0; i < 3; ++i) {
    float4 f = s4[lane + 64 * i];
    ushort4 h, l;
    h.x = f2bf(f.x); l.x = f2bf(f.x - bf2f(h.x));
    h.y = f2bf(f.y); l.y = f2bf(f.y - bf2f(h.y));
    h.z = f2bf(f.z); l.z = f2bf(f.z - bf2f(h.z));
    h.w = f2bf(f.w); l.w = f2bf(f.w - bf2f(h.w));
    h4[lane + 64 * i] = h;
    l4[lane + 64 * i] = l;
    acc += (f.x * f.x + f.y * f.y) + (f.z * f.z + f.w * f.w);
  }
#pragma unroll
  for (int off = 32; off > 0; off >>= 1) acc += __shfl_down(acc, off, 64);
  if (lane == 0) *ndst = acc;
}

// ---------------------------------------------------------------- phase 1
// Split-bf16 MFMA argmin. Block = 128 tokens x (all 4096 codes, looped in
// 128-code tiles). 4 waves in 2x2, each 64x64 via 4x4 grid of 16x16x32 MFMA.
// Score s = c2 - 2*(xh.ch + xh.cl + xl.ch); track best + second-best; flag
// tokens with gap < MARGIN for exact fp32 rescan.
__global__ __launch_bounds__(256, 2) void vq_mfma_kernel(
    const unsigned short* __restrict__ xh, const unsigned short* __restrict__ xl,
    const unsigned short* __restrict__ cbh, const unsigned short* __restrict__ cbl,
    const float* __restrict__ c2, int* __restrict__ out_idx,
    int* __restrict__ fcnt, int* __restrict__ flist) {
  __shared__ unsigned short sAh[4096], sAl[4096], sBh[4096], sBl[4096];  // 8KB ea
  __shared__ float redv[256], redsv[256];
  __shared__ int   redi[256];

  const int tid = threadIdx.x;
  const int wave = tid >> 6, lane = tid & 63;
  const int l15 = lane & 15, quad = lane >> 4;
  const int wr = wave >> 1, wc = wave & 1;
  const int tokBase = blockIdx.x * 128;

  // staging: chunk = wave*128 + inst*64 + lane; row = chunk>>2; c8 = (chunk&3)*8
  const int chunk0 = wave * 128 + lane;
  const int chunk1 = chunk0 + 64;
  const int r0 = chunk0 >> 2, c0 = (chunk0 & 3) * 8;
  const int r1 = chunk1 >> 2, c1 = (chunk1 & 3) * 8;
  const size_t aoffg0 = (size_t)(tokBase + r0) * CODE_DIM + c0;
  const size_t aoffg1 = (size_t)(tokBase + r1) * CODE_DIM + c1;
  const size_t boffg0 = (size_t)r0 * CODE_DIM + c0;
  const size_t boffg1 = (size_t)r1 * CODE_DIM + c1;
  unsigned short* ldsA0 = &sAh[wave * 1024];       // uniform per wave
  unsigned short* ldsA1 = &sAh[wave * 1024 + 512];
  unsigned short* ldsAl0 = &sAl[wave * 1024];
  unsigned short* ldsAl1 = &sAl[wave * 1024 + 512];
  unsigned short* ldsB0 = &sBh[wave * 1024];
  unsigned short* ldsB1 = &sBh[wave * 1024 + 512];
  unsigned short* ldsBl0 = &sBl[wave * 1024];
  unsigned short* ldsBl1 = &sBl[wave * 1024 + 512];

  const int aoffL = (wr * 64 + l15) * 32 + quad * 8;  // + i*512
  const int boffL = (wc * 64 + l15) * 32 + quad * 8;  // + j*512

  float v[4][4], sv[4][4];
  int bi[4][4];
#pragma unroll
  for (int i = 0; i < 4; ++i)
#pragma unroll
    for (int r = 0; r < 4; ++r) { v[i][r] = FLTMAX; sv[i][r] = FLTMAX; bi[i][r] = 0; }

  for (int kt = 0; kt < NUM_CODES / 128; ++kt) {
    const int kbase = kt * 128;
    const size_t kb768 = (size_t)kbase * CODE_DIM;
    f32x4 acc[4][4];
#pragma unroll
    for (int i = 0; i < 4; ++i)
#pragma unroll
      for (int j = 0; j < 4; ++j) acc[i][j] = (f32x4){0.f, 0.f, 0.f, 0.f};

    for (int ks = 0; ks < CODE_DIM / 32; ++ks) {
      const int k0 = ks * 32;
      __syncthreads();  // prior frag reads done before restage
      gl2lds16(xh + aoffg0 + k0, ldsA0);
      gl2lds16(xh + aoffg1 + k0, ldsA1);
      gl2lds16(xl + aoffg0 + k0, ldsAl0);
      gl2lds16(xl + aoffg1 + k0, ldsAl1);
      gl2lds16(cbh + boffg0 + kb768 + k0, ldsB0);
      gl2lds16(cbh + boffg1 + kb768 + k0, ldsB1);
      gl2lds16(cbl + boffg0 + kb768 + k0, ldsBl0);
      gl2lds16(cbl + boffg1 + kb768 + k0, ldsBl1);
      __syncthreads();  // vmcnt drain + barrier

      bf16x8 fah[4], fal[4], fbh[4], fbl[4];
#pragma unroll
      for (int i = 0; i < 4; ++i) {
        fah[i] = *(const bf16x8*)&sAh[aoffL + i * 512];
        fal[i] = *(const bf16x8*)&sAl[aoffL + i * 512];
      }
#pragma unroll
      for (int j = 0; j < 4; ++j) {
        fbh[j] = *(const bf16x8*)&sBh[boffL + j * 512];
        fbl[j] = *(const bf16x8*)&sBl[boffL + j * 512];
      }
#pragma unroll
      for (int i = 0; i < 4; ++i)
#pragma unroll
        for (int j = 0; j < 4; ++j) {
          acc[i][j] = __builtin_amdgcn_mfma_f32_16x16x32_bf16(fah[i], fbh[j], acc[i][j], 0, 0, 0);
          acc[i][j] = __builtin_amdgcn_mfma_f32_16x16x32_bf16(fah[i], fbl[j], acc[i][j], 0, 0, 0);
          acc[i][j] = __builtin_amdgcn_mfma_f32_16x16x32_bf16(fal[i], fbh[j], acc[i][j], 0, 0, 0);
        }
    }

    // epilogue: s = c2 - 2*dot; maintain (best, second, idx) per token slot
#pragma unroll
    for (int j = 0; j < 4; ++j) {
      const int kcol = kbase + wc * 64 + j * 16 + l15;
      const float c2j = c2[kcol];
#pragma unroll
      for (int i = 0; i < 4; ++i)
#pragma unroll
        for (int r = 0; r < 4; ++r) {
          float s = fmaf(-2.0f, acc[i][j][r], c2j);
          float vo = v[i][r];
          sv[i][r] = fminf(sv[i][r], fmaxf(s, vo));  // med3(s, v, sv)
          bool lt = s < vo;
          v[i][r]  = lt ? s : vo;
          bi[i][r] = lt ? kcol : bi[i][r];
        }
    }
  }

  // butterfly reduce across the 16 lanes sharing a token row
#pragma unroll
  for (int i = 0; i < 4; ++i)
#pragma unroll
    for (int r = 0; r < 4; ++r) {
      float vv = v[i][r], svv = sv[i][r];
      int ii = bi[i][r];
#pragma unroll
      for (int m = 1; m < 16; m <<= 1) {
        float ov = __shfl_xor(vv, m, 64);
        float osv = __shfl_xor(svv, m, 64);
        int oi = __shfl_xor(ii, m, 64);
        float nsv = fminf(fminf(svv, osv), fmaxf(vv, ov));
        bool take = (ov < vv) || (ov == vv && oi < ii);
        vv = take ? ov : vv;
        ii = take ? oi : ii;
        svv = nsv;
      }
      if (l15 == 0) {
        int row = wr * 64 + i * 16 + quad * 4 + r;
        redv[row * 2 + wc] = vv;
        redsv[row * 2 + wc] = svv;
        redi[row * 2 + wc] = ii;
      }
    }
  __syncthreads();
  if (tid < 128) {
    float v0 = redv[tid * 2], v1 = redv[tid * 2 + 1];
    float s0 = redsv[tid * 2], s1 = redsv[tid * 2 + 1];
    int i0 = redi[tid * 2], i1 = redi[tid * 2 + 1];
    bool take = (v1 < v0) || (v1 == v0 && i1 < i0);
    float bv = take ? v1 : v0;
    int bidx = take ? i1 : i0;
    float bsv = fminf(fminf(s0, s1), fmaxf(v0, v1));
    out_idx[tokBase + tid] = bidx;
    if (bsv - bv < MARGIN) {
      int p = atomicAdd(fcnt, 1);
      flist[p] = tokBase + tid;
    }
  }
}

// ---------------------------------------------------------------- rescan
// Exact fp32 full scan for flagged tokens (replicates round-1 math & order).
__global__ __launch_bounds__(256) void vq_rescan_kernel(
    const float* __restrict__ x, const float* __restrict__ cb,
    const float* __restrict__ x2, const float* __restrict__ c2,
    const int* __restrict__ fcnt, const int* __restrict__ flist,
    int* __restrict__ out_idx) {
  __shared__ float xs[CODE_DIM];
  __shared__ float rv[256];
  __shared__ int ri[256];
  const int nf = *fcnt;
  for (int f = blockIdx.x; f < nf; f += gridDim.x) {
    const int tok = flist[f];
    __syncthreads();
    if (threadIdx.x < 192)
      ((float4*)xs)[threadIdx.x] = ((const float4*)(x + (size_t)tok * CODE_DIM))[threadIdx.x];
    __syncthreads();
    const float xx = x2[tok];
    float bv = FLTMAX;
    int bidx = 0;
    for (int kk = 0; kk < NUM_CODES / 256; ++kk) {
      const int k = kk * 256 + threadIdx.x;
      const float4* crow = (const float4*)(cb + (size_t)k * CODE_DIM);
      float acc = 0.f;
      for (int c = 0; c < CODE_DIM / 4; ++c) {
        float4 cv = crow[c];
        float4 xv = ((float4*)xs)[c];
        acc += (xv.x * cv.x + xv.y * cv.y) + (xv.z * cv.z + xv.w * cv.w);
      }
      float dist = (xx + c2[k]) - 2.0f * acc;
      if (dist < bv) { bv = dist; bidx = k; }
    }
    rv[threadIdx.x] = bv;
    ri[threadIdx.x] = bidx;
    __syncthreads();
    for (int s = 128; s > 0; s >>= 1) {
      if (threadIdx.x < s) {
        float ov = rv[threadIdx.x + s];
        int oi = ri[threadIdx.x + s];
        if (ov < rv[threadIdx.x] || (ov == rv[threadIdx.x] && oi < ri[threadIdx.x])) {
          rv[threadIdx.x] = ov;
          ri[threadIdx.x] = oi;
        }
      }
      __syncthreads();
    }
    if (threadIdx.x == 0) out_idx[tok] = ri[0];
  }
}

// ---------------------------------------------------------------- gather
__global__ __launch_bounds__(256) void vq_gather_kernel(
    const float* __restrict__ cb, const int* __restrict__ idx,
    float* __restrict__ out) {
  const int wave = threadIdx.x >> 6;
  const int lane = threadIdx.x & 63;
  const int token = blockIdx.x * 4 + wave;
  const int k = idx[token];
  const float4* src = (const float4*)(cb + (size_t)k * CODE_DIM);
  float4* dst = (float4*)(out + (size_t)token * CODE_DIM);
#pragma unroll
  for (int i = 0; i < 3; ++i) dst[lane + 64 * i] = src[lane + 64 * i];
  if (lane == 0) out[(size_t)N_TOKENS * CODE_DIM + token] = (float)k;
}

// ================================================================ fallback
// Round-1 fp32 path (used only if ws_size is too small for the split buffers)
#define MT 64
#define KT 128
#define DT 32
#define LDSTRIDE 36

__global__ __launch_bounds__(256) void vq_norms_kernel(
    const float* __restrict__ x, const float* __restrict__ cb,
    float* __restrict__ x2, float* __restrict__ c2) {
  const int wave = threadIdx.x >> 6;
  const int lane = threadIdx.x & 63;
  const int row = blockIdx.x * 4 + wave;
  const float* src;
  float* dst;
  if (row < N_TOKENS) {
    src = x + (size_t)row * CODE_DIM;
    dst = x2 + row;
  } else {
    const int r = row - N_TOKENS;
    if (r >= NUM_CODES) return;
    src = cb + (size_t)r * CODE_DIM;
    dst = c2 + r;
  }
  const float4* s4 = (const float4*)src;
  float acc = 0.f;
#pragma unroll
  for (int i = 0; i < 3; ++i) {
    float4 vv = s4[lane + 64 * i];
    acc += (vv.x * vv.x + vv.y * vv.y) + (vv.z * vv.z + vv.w * vv.w);
  }
#pragma unroll
  for (int off = 32; off > 0; off >>= 1) acc += __shfl_down(acc, off, 64);
  if (lane == 0) *dst = acc;
}

__global__ __launch_bounds__(256) void vq_argmin_kernel(
    const float* __restrict__ x, const float* __restrict__ cb,
    const float* __restrict__ x2, const float* __restrict__ c2,
    int* __restrict__ out_idx) {
  __shared__ float xs[MT * LDSTRIDE];
  __shared__ float cs[KT * LDSTRIDE];
  __shared__ float x2s[MT];
  __shared__ float c2s[KT];
  const int tid = threadIdx.x;
  const int tx = tid & 15;
  const int ty = tid >> 4;
  const int tokBase = blockIdx.x * MT;
  if (tid < MT) x2s[tid] = x2[tokBase + tid];
  float bestv[4];
  int besti[4];
#pragma unroll
  for (int i = 0; i < 4; ++i) { bestv[i] = FLTMAX; besti[i] = 0; }
  const float4* xg = (const float4*)x;
  const float4* cg = (const float4*)cb;
  for (int kt = 0; kt < NUM_CODES / KT; ++kt) {
    const int kBase = kt * KT;
    __syncthreads();
    if (tid < KT) c2s[tid] = c2[kBase + tid];
    float acc[4][8];
#pragma unroll
    for (int i = 0; i < 4; ++i)
#pragma unroll
      for (int j = 0; j < 8; ++j) acc[i][j] = 0.f;
    for (int dc = 0; dc < CODE_DIM / DT; ++dc) {
      __syncthreads();
#pragma unroll
      for (int r = 0; r < 2; ++r) {
        int fidx = tid + 256 * r;
        int row = fidx >> 3, c4 = fidx & 7;
        float4 vv = xg[(size_t)(tokBase + row) * (CODE_DIM / 4) + dc * 8 + c4];
        *(float4*)&xs[row * LDSTRIDE + c4 * 4] = vv;
      }
#pragma unroll
      for (int r = 0; r < 4; ++r) {
        int fidx = tid + 256 * r;
        int row = fidx >> 3, c4 = fidx & 7;
        float4 vv = cg[(size_t)(kBase + row) * (CODE_DIM / 4) + dc * 8 + c4];
        *(float4*)&cs[row * LDSTRIDE + c4 * 4] = vv;
      }
      __syncthreads();
#pragma unroll
      for (int dd = 0; dd < DT / 4; ++dd) {
        float4 xv[4], cv[8];
#pragma unroll
        for (int i = 0; i < 4; ++i)
          xv[i] = *(const float4*)&xs[(ty + 16 * i) * LDSTRIDE + dd * 4];
#pragma unroll
        for (int j = 0; j < 8; ++j)
          cv[j] = *(const float4*)&cs[(tx + 16 * j) * LDSTRIDE + dd * 4];
#pragma unroll
        for (int i = 0; i < 4; ++i)
#pragma unroll
          for (int j = 0; j < 8; ++j)
            acc[i][j] += (xv[i].x * cv[j].x + xv[i].y * cv[j].y) +
                         (xv[i].z * cv[j].z + xv[i].w * cv[j].w);
      }
    }
#pragma unroll
    for (int i = 0; i < 4; ++i) {
      const float xx = x2s[ty + 16 * i];
#pragma unroll
      for (int j = 0; j < 8; ++j) {
        float dist = (xx + c2s[tx + 16 * j]) - 2.0f * acc[i][j];
        int k = kBase + tx + 16 * j;
        if (dist < bestv[i]) { bestv[i] = dist; besti[i] = k; }
      }
    }
  }
  __syncthreads();
  float* rdv = xs;
  int* rdi = (int*)cs;
#pragma unroll
  for (int i = 0; i < 4; ++i) {
    const int m = ty + 16 * i;
    rdv[m * 16 + tx] = bestv[i];
    rdi[m * 16 + tx] = besti[i];
  }
  __syncthreads();
  if (tid < MT) {
    float bv = rdv[tid * 16];
    int bidx = rdi[tid * 16];
#pragma unroll
    for (int t = 1; t < 16; ++t) {
      float vv = rdv[tid * 16 + t];
      int kk = rdi[tid * 16 + t];
      if (vv < bv || (vv == bv && kk < bidx)) { bv = vv; bidx = kk; }
    }
    out_idx[tokBase + tid] = bidx;
  }
}

// ---------------------------------------------------------------- launch
extern "C" void kernel_launch(void* const* d_in, const int* in_sizes, int n_in,
                              void* d_out, int out_size, void* d_ws, size_t ws_size,
                              hipStream_t stream) {
  (void)in_sizes; (void)n_in; (void)out_size;
  const float* x = (const float*)d_in[0];
  const float* cb = (const float*)d_in[1];
  float* out = (float*)d_out;

  // ws carve (MFMA path)
  char* w = (char*)d_ws;
  unsigned short* xh = (unsigned short*)w;  w += (size_t)N_TOKENS * CODE_DIM * 2;
  unsigned short* xl = (unsigned short*)w;  w += (size_t)N_TOKENS * CODE_DIM * 2;
  unsigned short* cbh = (unsigned short*)w; w += (size_t)NUM_CODES * CODE_DIM * 2;
  unsigned short* cbl = (unsigned short*)w; w += (size_t)NUM_CODES * CODE_DIM * 2;
  float* x2 = (float*)w;  w += (size_t)N_TOKENS * 4;
  float* c2 = (float*)w;  w += (size_t)NUM_CODES * 4;
  int* idx = (int*)w;     w += (size_t)N_TOKENS * 4;
  int* flist = (int*)w;   w += (size_t)N_TOKENS * 4;
  int* fcnt = (int*)w;    w += 256;
  const size_t need = (size_t)(w - (char*)d_ws);

  if (ws_size >= need) {
    vq_convert_kernel<<<(N_TOKENS + NUM_CODES) / 4, 256, 0, stream>>>(
        x, cb, xh, xl, cbh, cbl, x2, c2, fcnt);
    vq_mfma_kernel<<<N_TOKENS / 128, 256, 0, stream>>>(
        xh, xl, cbh, cbl, c2, idx, fcnt, flist);
    vq_rescan_kernel<<<512, 256, 0, stream>>>(x, cb, x2, c2, fcnt, flist, idx);
    vq_gather_kernel<<<N_TOKENS / 4, 256, 0, stream>>>(cb, idx, out);
  } else {
    // fallback: round-1 fp32 path
    float* fx2 = (float*)d_ws;
    float* fc2 = fx2 + N_TOKENS;
    int* fidx = (int*)(fc2 + NUM_CODES);
    vq_norms_kernel<<<(N_TOKENS + NUM_CODES + 3) / 4, 256, 0, stream>>>(x, cb, fx2, fc2);
    vq_argmin_kernel<<<N_TOKENS / MT, 256, 0, stream>>>(x, cb, fx2, fc2, fidx);
    vq_gather_kernel<<<N_TOKENS / 4, 256, 0, stream>>>(cb, fidx, out);
  }
}

// Round 3
// 1743.698 us; speedup vs baseline: 8.9696x; 1.1936x over previous
//
#include <hip/hip_runtime.h>

// Problem constants (fixed by reference)
#define N_TOKENS  65536
#define CODE_DIM  768
#define NUM_CODES 4096

#define MARGIN 0.006f
#define FLTMAX 3.4028235e38f

typedef __attribute__((ext_vector_type(8))) short bf16x8;
typedef __attribute__((ext_vector_type(4))) float f32x4;

// ---------------------------------------------------------------- helpers
__device__ __forceinline__ unsigned short f2bf(float f) {
  unsigned int u = __float_as_uint(f);
  unsigned int r = (u + 0x7fffu + ((u >> 16) & 1u)) >> 16;  // RN-even
  return (unsigned short)r;
}
__device__ __forceinline__ float bf2f(unsigned short h) {
  return __uint_as_float(((unsigned int)h) << 16);
}
__device__ __forceinline__ void gl2lds16(const void* g, void* l) {
  __builtin_amdgcn_global_load_lds(
      (const __attribute__((address_space(1))) unsigned int*)g,
      (__attribute__((address_space(3))) unsigned int*)l, 16, 0, 0);
}

// ---------------------------------------------------------------- convert
// One wave per row: split fp32 -> (hi, lo) bf16 and compute squared norm.
__global__ __launch_bounds__(256) void vq_convert_kernel(
    const float* __restrict__ x, const float* __restrict__ cb,
    unsigned short* __restrict__ xh, unsigned short* __restrict__ xl,
    unsigned short* __restrict__ cbh, unsigned short* __restrict__ cbl,
    float* __restrict__ x2, float* __restrict__ c2, int* __restrict__ fcnt) {
  if (blockIdx.x == 0 && threadIdx.x == 0) *fcnt = 0;
  const int wave = threadIdx.x >> 6;
  const int lane = threadIdx.x & 63;
  const int row  = blockIdx.x * 4 + wave;
  const float* src;
  unsigned short *hdst, *ldst;
  float* ndst;
  if (row < N_TOKENS) {
    src = x + (size_t)row * CODE_DIM;
    hdst = xh + (size_t)row * CODE_DIM;
    ldst = xl + (size_t)row * CODE_DIM;
    ndst = x2 + row;
  } else {
    const int r = row - N_TOKENS;
    if (r >= NUM_CODES) return;
    src = cb + (size_t)r * CODE_DIM;
    hdst = cbh + (size_t)r * CODE_DIM;
    ldst = cbl + (size_t)r * CODE_DIM;
    ndst = c2 + r;
  }
  const float4* s4 = (const float4*)src;
  ushort4* h4 = (ushort4*)hdst;
  ushort4* l4 = (ushort4*)ldst;
  float acc = 0.f;
#pragma unroll
  for (int i = 0; i < 3; ++i) {
    float4 f = s4[lane + 64 * i];
    ushort4 h, l;
    h.x = f2bf(f.x); l.x = f2bf(f.x - bf2f(h.x));
    h.y = f2bf(f.y); l.y = f2bf(f.y - bf2f(h.y));
    h.z = f2bf(f.z); l.z = f2bf(f.z - bf2f(h.z));
    h.w = f2bf(f.w); l.w = f2bf(f.w - bf2f(h.w));
    h4[lane + 64 * i] = h;
    l4[lane + 64 * i] = l;
    acc += (f.x * f.x + f.y * f.y) + (f.z * f.z + f.w * f.w);
  }
#pragma unroll
  for (int off = 32; off > 0; off >>= 1) acc += __shfl_down(acc, off, 64);
  if (lane == 0) *ndst = acc;
}

// ---------------------------------------------------------------- phase 1
// Split-bf16 MFMA argmin, BK=64, XOR-swizzled LDS (conflict-free ds_read_b128).
// Block = 128 tokens x 128-code tiles over all 4096 codes. 4 waves 2x2,
// each 64x64 via 4x4 of 16x16x32 MFMA, 3 passes (hh, hl, lh).
// LDS layout per buffer: 128 rows x 64 cols bf16; chunk (r, c) of 8 bf16
// stored at position r*8 + (c ^ (r&7)). Staged via global_load_lds with the
// XOR applied to the *global* source column so LDS dests stay lane-linear.
__global__ __launch_bounds__(256, 2) void vq_mfma_kernel(
    const unsigned short* __restrict__ xh, const unsigned short* __restrict__ xl,
    const unsigned short* __restrict__ cbh, const unsigned short* __restrict__ cbl,
    const float* __restrict__ c2, int* __restrict__ out_idx,
    int* __restrict__ fcnt, int* __restrict__ flist) {
  __shared__ unsigned short sAh[8192], sAl[8192], sBh[8192], sBl[8192];  // 16KB ea
  __shared__ float redv[256], redsv[256];
  __shared__ int   redi[256];

  const int tid = threadIdx.x;
  const int wave = tid >> 6, lane = tid & 63;
  const int l15 = lane & 15, quad = lane >> 4;
  const int wr = wave >> 1, wc = wave & 1;
  const int tokBase = blockIdx.x * 128;

  // ---- staging addressing (per wave: 32 rows x 8 chunks, 4 insts/buffer)
  // inst t, lane: chunk id = t*64+lane -> r = t*8 + (lane>>3), c = lane&7
  // swizzled source column chunk = c ^ (r&7) = (lane&7) ^ ((lane>>3)&7)
  const int lr = lane >> 3;                       // 0..7
  const int cSrc = (lane & 7) ^ (lr & 7);
  const size_t aOff = (size_t)(tokBase + wave * 32 + lr) * CODE_DIM + cSrc * 8;
  const size_t bOff = (size_t)(wave * 32 + lr) * CODE_DIM + cSrc * 8;
  // LDS dest bases (shorts), wave-uniform: wave*2048 + t*512

  // ---- fragment read addressing
  const int swz = l15 & 7;
  const int arow = (wr * 64 + l15) * 64;  // + i*1024 + coffq
  const int brow = (wc * 64 + l15) * 64;  // + j*1024 + coffq

  float v[4][4], sv[4][4];
  int bi[4][4];
#pragma unroll
  for (int i = 0; i < 4; ++i)
#pragma unroll
    for (int r = 0; r < 4; ++r) { v[i][r] = FLTMAX; sv[i][r] = FLTMAX; bi[i][r] = 0; }

  for (int kt = 0; kt < NUM_CODES / 128; ++kt) {
    const int kbase = kt * 128;
    const size_t kb = (size_t)kbase * CODE_DIM;
    f32x4 acc[4][4];
#pragma unroll
    for (int i = 0; i < 4; ++i)
#pragma unroll
      for (int j = 0; j < 4; ++j) acc[i][j] = (f32x4){0.f, 0.f, 0.f, 0.f};

    for (int ks = 0; ks < CODE_DIM / 64; ++ks) {
      const int k0 = ks * 64;
      __syncthreads();  // prior frag reads done before restage
#pragma unroll
      for (int t = 0; t < 4; ++t) {
        const size_t ga = aOff + t * (8 * CODE_DIM) + k0;
        const size_t gb = bOff + kb + t * (8 * CODE_DIM) + k0;
        const int ld = wave * 2048 + t * 512;
        gl2lds16(xh + ga, &sAh[ld]);
        gl2lds16(xl + ga, &sAl[ld]);
        gl2lds16(cbh + gb, &sBh[ld]);
        gl2lds16(cbl + gb, &sBl[ld]);
      }
      __syncthreads();  // vmcnt drain + barrier

#pragma unroll
      for (int ks2 = 0; ks2 < 2; ++ks2) {
        const int coffq = ((ks2 * 4 + quad) ^ swz) * 8;
        bf16x8 fah[4], fal[4], fbh[4], fbl[4];
#pragma unroll
        for (int i = 0; i < 4; ++i) {
          fah[i] = *(const bf16x8*)&sAh[arow + i * 1024 + coffq];
          fal[i] = *(const bf16x8*)&sAl[arow + i * 1024 + coffq];
        }
#pragma unroll
        for (int j = 0; j < 4; ++j) {
          fbh[j] = *(const bf16x8*)&sBh[brow + j * 1024 + coffq];
          fbl[j] = *(const bf16x8*)&sBl[brow + j * 1024 + coffq];
        }
#pragma unroll
        for (int i = 0; i < 4; ++i)
#pragma unroll
          for (int j = 0; j < 4; ++j) {
            acc[i][j] = __builtin_amdgcn_mfma_f32_16x16x32_bf16(fah[i], fbh[j], acc[i][j], 0, 0, 0);
            acc[i][j] = __builtin_amdgcn_mfma_f32_16x16x32_bf16(fah[i], fbl[j], acc[i][j], 0, 0, 0);
            acc[i][j] = __builtin_amdgcn_mfma_f32_16x16x32_bf16(fal[i], fbh[j], acc[i][j], 0, 0, 0);
          }
      }
    }

    // epilogue: s = c2 - 2*dot; maintain (best, second, idx) per token slot
#pragma unroll
    for (int j = 0; j < 4; ++j) {
      const int kcol = kbase + wc * 64 + j * 16 + l15;
      const float c2j = c2[kcol];
#pragma unroll
      for (int i = 0; i < 4; ++i)
#pragma unroll
        for (int r = 0; r < 4; ++r) {
          float s = fmaf(-2.0f, acc[i][j][r], c2j);
          float vo = v[i][r];
          sv[i][r] = fminf(sv[i][r], fmaxf(s, vo));  // med3(s, v, sv)
          bool lt = s < vo;
          v[i][r]  = lt ? s : vo;
          bi[i][r] = lt ? kcol : bi[i][r];
        }
    }
  }

  // butterfly reduce across the 16 lanes sharing a token row
#pragma unroll
  for (int i = 0; i < 4; ++i)
#pragma unroll
    for (int r = 0; r < 4; ++r) {
      float vv = v[i][r], svv = sv[i][r];
      int ii = bi[i][r];
#pragma unroll
      for (int m = 1; m < 16; m <<= 1) {
        float ov = __shfl_xor(vv, m, 64);
        float osv = __shfl_xor(svv, m, 64);
        int oi = __shfl_xor(ii, m, 64);
        float nsv = fminf(fminf(svv, osv), fmaxf(vv, ov));
        bool take = (ov < vv) || (ov == vv && oi < ii);
        vv = take ? ov : vv;
        ii = take ? oi : ii;
        svv = nsv;
      }
      if (l15 == 0) {
        int row = wr * 64 + i * 16 + quad * 4 + r;
        redv[row * 2 + wc] = vv;
        redsv[row * 2 + wc] = svv;
        redi[row * 2 + wc] = ii;
      }
    }
  __syncthreads();
  if (tid < 128) {
    float v0 = redv[tid * 2], v1 = redv[tid * 2 + 1];
    float s0 = redsv[tid * 2], s1 = redsv[tid * 2 + 1];
    int i0 = redi[tid * 2], i1 = redi[tid * 2 + 1];
    bool take = (v1 < v0) || (v1 == v0 && i1 < i0);
    float bv = take ? v1 : v0;
    int bidx = take ? i1 : i0;
    float bsv = fminf(fminf(s0, s1), fmaxf(v0, v1));
    out_idx[tokBase + tid] = bidx;
    if (bsv - bv < MARGIN) {
      int p = atomicAdd(fcnt, 1);
      flist[p] = tokBase + tid;
    }
  }
}

// ---------------------------------------------------------------- rescan
// Exact fp32 full scan for flagged tokens (replicates round-1 math & order).
__global__ __launch_bounds__(256) void vq_rescan_kernel(
    const float* __restrict__ x, const float* __restrict__ cb,
    const float* __restrict__ x2, const float* __restrict__ c2,
    const int* __restrict__ fcnt, const int* __restrict__ flist,
    int* __restrict__ out_idx) {
  __shared__ float xs[CODE_DIM];
  __shared__ float rv[256];
  __shared__ int ri[256];
  const int nf = *fcnt;
  for (int f = blockIdx.x; f < nf; f += gridDim.x) {
    const int tok = flist[f];
    __syncthreads();
    if (threadIdx.x < 192)
      ((float4*)xs)[threadIdx.x] = ((const float4*)(x + (size_t)tok * CODE_DIM))[threadIdx.x];
    __syncthreads();
    const float xx = x2[tok];
    float bv = FLTMAX;
    int bidx = 0;
    for (int kk = 0; kk < NUM_CODES / 256; ++kk) {
      const int k = kk * 256 + threadIdx.x;
      const float4* crow = (const float4*)(cb + (size_t)k * CODE_DIM);
      float acc = 0.f;
      for (int c = 0; c < CODE_DIM / 4; ++c) {
        float4 cv = crow[c];
        float4 xv = ((float4*)xs)[c];
        acc += (xv.x * cv.x + xv.y * cv.y) + (xv.z * cv.z + xv.w * cv.w);
      }
      float dist = (xx + c2[k]) - 2.0f * acc;
      if (dist < bv) { bv = dist; bidx = k; }
    }
    rv[threadIdx.x] = bv;
    ri[threadIdx.x] = bidx;
    __syncthreads();
    for (int s = 128; s > 0; s >>= 1) {
      if (threadIdx.x < s) {
        float ov = rv[threadIdx.x + s];
        int oi = ri[threadIdx.x + s];
        if (ov < rv[threadIdx.x] || (ov == rv[threadIdx.x] && oi < ri[threadIdx.x])) {
          rv[threadIdx.x] = ov;
          ri[threadIdx.x] = oi;
        }
      }
      __syncthreads();
    }
    if (threadIdx.x == 0) out_idx[tok] = ri[0];
  }
}

// ---------------------------------------------------------------- gather
__global__ __launch_bounds__(256) void vq_gather_kernel(
    const float* __restrict__ cb, const int* __restrict__ idx,
    float* __restrict__ out) {
  const int wave = threadIdx.x >> 6;
  const int lane = threadIdx.x & 63;
  const int token = blockIdx.x * 4 + wave;
  const int k = idx[token];
  const float4* src = (const float4*)(cb + (size_t)k * CODE_DIM);
  float4* dst = (float4*)(out + (size_t)token * CODE_DIM);
#pragma unroll
  for (int i = 0; i < 3; ++i) dst[lane + 64 * i] = src[lane + 64 * i];
  if (lane == 0) out[(size_t)N_TOKENS * CODE_DIM + token] = (float)k;
}

// ================================================================ fallback
// Round-1 fp32 path (used only if ws_size is too small for the split buffers)
#define MT 64
#define KT 128
#define DT 32
#define LDSTRIDE 36

__global__ __launch_bounds__(256) void vq_norms_kernel(
    const float* __restrict__ x, const float* __restrict__ cb,
    float* __restrict__ x2, float* __restrict__ c2) {
  const int wave = threadIdx.x >> 6;
  const int lane = threadIdx.x & 63;
  const int row = blockIdx.x * 4 + wave;
  const float* src;
  float* dst;
  if (row < N_TOKENS) {
    src = x + (size_t)row * CODE_DIM;
    dst = x2 + row;
  } else {
    const int r = row - N_TOKENS;
    if (r >= NUM_CODES) return;
    src = cb + (size_t)r * CODE_DIM;
    dst = c2 + r;
  }
  const float4* s4 = (const float4*)src;
  float acc = 0.f;
#pragma unroll
  for (int i = 0; i < 3; ++i) {
    float4 vv = s4[lane + 64 * i];
    acc += (vv.x * vv.x + vv.y * vv.y) + (vv.z * vv.z + vv.w * vv.w);
  }
#pragma unroll
  for (int off = 32; off > 0; off >>= 1) acc += __shfl_down(acc, off, 64);
  if (lane == 0) *dst = acc;
}

__global__ __launch_bounds__(256) void vq_argmin_kernel(
    const float* __restrict__ x, const float* __restrict__ cb,
    const float* __restrict__ x2, const float* __restrict__ c2,
    int* __restrict__ out_idx) {
  __shared__ float xs[MT * LDSTRIDE];
  __shared__ float cs[KT * LDSTRIDE];
  __shared__ float x2s[MT];
  __shared__ float c2s[KT];
  const int tid = threadIdx.x;
  const int tx = tid & 15;
  const int ty = tid >> 4;
  const int tokBase = blockIdx.x * MT;
  if (tid < MT) x2s[tid] = x2[tokBase + tid];
  float bestv[4];
  int besti[4];
#pragma unroll
  for (int i = 0; i < 4; ++i) { bestv[i] = FLTMAX; besti[i] = 0; }
  const float4* xg = (const float4*)x;
  const float4* cg = (const float4*)cb;
  for (int kt = 0; kt < NUM_CODES / KT; ++kt) {
    const int kBase = kt * KT;
    __syncthreads();
    if (tid < KT) c2s[tid] = c2[kBase + tid];
    float acc[4][8];
#pragma unroll
    for (int i = 0; i < 4; ++i)
#pragma unroll
      for (int j = 0; j < 8; ++j) acc[i][j] = 0.f;
    for (int dc = 0; dc < CODE_DIM / DT; ++dc) {
      __syncthreads();
#pragma unroll
      for (int r = 0; r < 2; ++r) {
        int fidx = tid + 256 * r;
        int row = fidx >> 3, c4 = fidx & 7;
        float4 vv = xg[(size_t)(tokBase + row) * (CODE_DIM / 4) + dc * 8 + c4];
        *(float4*)&xs[row * LDSTRIDE + c4 * 4] = vv;
      }
#pragma unroll
      for (int r = 0; r < 4; ++r) {
        int fidx = tid + 256 * r;
        int row = fidx >> 3, c4 = fidx & 7;
        float4 vv = cg[(size_t)(kBase + row) * (CODE_DIM / 4) + dc * 8 + c4];
        *(float4*)&cs[row * LDSTRIDE + c4 * 4] = vv;
      }
      __syncthreads();
#pragma unroll
      for (int dd = 0; dd < DT / 4; ++dd) {
        float4 xv[4], cv[8];
#pragma unroll
        for (int i = 0; i < 4; ++i)
          xv[i] = *(const float4*)&xs[(ty + 16 * i) * LDSTRIDE + dd * 4];
#pragma unroll
        for (int j = 0; j < 8; ++j)
          cv[j] = *(const float4*)&cs[(tx + 16 * j) * LDSTRIDE + dd * 4];
#pragma unroll
        for (int i = 0; i < 4; ++i)
#pragma unroll
          for (int j = 0; j < 8; ++j)
            acc[i][j] += (xv[i].x * cv[j].x + xv[i].y * cv[j].y) +
                         (xv[i].z * cv[j].z + xv[i].w * cv[j].w);
      }
    }
#pragma unroll
    for (int i = 0; i < 4; ++i) {
      const float xx = x2s[ty + 16 * i];
#pragma unroll
      for (int j = 0; j < 8; ++j) {
        float dist = (xx + c2s[tx + 16 * j]) - 2.0f * acc[i][j];
        int k = kBase + tx + 16 * j;
        if (dist < bestv[i]) { bestv[i] = dist; besti[i] = k; }
      }
    }
  }
  __syncthreads();
  float* rdv = xs;
  int* rdi = (int*)cs;
#pragma unroll
  for (int i = 0; i < 4; ++i) {
    const int m = ty + 16 * i;
    rdv[m * 16 + tx] = bestv[i];
    rdi[m * 16 + tx] = besti[i];
  }
  __syncthreads();
  if (tid < MT) {
    float bv = rdv[tid * 16];
    int bidx = rdi[tid * 16];
#pragma unroll
    for (int t = 1; t < 16; ++t) {
      float vv = rdv[tid * 16 + t];
      int kk = rdi[tid * 16 + t];
      if (vv < bv || (vv == bv && kk < bidx)) { bv = vv; bidx = kk; }
    }
    out_idx[tokBase + tid] = bidx;
  }
}

// ---------------------------------------------------------------- launch
extern "C" void kernel_launch(void* const* d_in, const int* in_sizes, int n_in,
                              void* d_out, int out_size, void* d_ws, size_t ws_size,
                              hipStream_t stream) {
  (void)in_sizes; (void)n_in; (void)out_size;
  const float* x = (const float*)d_in[0];
  const float* cb = (const float*)d_in[1];
  float* out = (float*)d_out;

  // ws carve (MFMA path)
  char* w = (char*)d_ws;
  unsigned short* xh = (unsigned short*)w;  w += (size_t)N_TOKENS * CODE_DIM * 2;
  unsigned short* xl = (unsigned short*)w;  w += (size_t)N_TOKENS * CODE_DIM * 2;
  unsigned short* cbh = (unsigned short*)w; w += (size_t)NUM_CODES * CODE_DIM * 2;
  unsigned short* cbl = (unsigned short*)w; w += (size_t)NUM_CODES * CODE_DIM * 2;
  float* x2 = (float*)w;  w += (size_t)N_TOKENS * 4;
  float* c2 = (float*)w;  w += (size_t)NUM_CODES * 4;
  int* idx = (int*)w;     w += (size_t)N_TOKENS * 4;
  int* flist = (int*)w;   w += (size_t)N_TOKENS * 4;
  int* fcnt = (int*)w;    w += 256;
  const size_t need = (size_t)(w - (char*)d_ws);

  if (ws_size >= need) {
    vq_convert_kernel<<<(N_TOKENS + NUM_CODES) / 4, 256, 0, stream>>>(
        x, cb, xh, xl, cbh, cbl, x2, c2, fcnt);
    vq_mfma_kernel<<<N_TOKENS / 128, 256, 0, stream>>>(
        xh, xl, cbh, cbl, c2, idx, fcnt, flist);
    vq_rescan_kernel<<<512, 256, 0, stream>>>(x, cb, x2, c2, fcnt, flist, idx);
    vq_gather_kernel<<<N_TOKENS / 4, 256, 0, stream>>>(cb, idx, out);
  } else {
    // fallback: round-1 fp32 path
    float* fx2 = (float*)d_ws;
    float* fc2 = fx2 + N_TOKENS;
    int* fidx = (int*)(fc2 + NUM_CODES);
    vq_norms_kernel<<<(N_TOKENS + NUM_CODES + 3) / 4, 256, 0, stream>>>(x, cb, fx2, fc2);
    vq_argmin_kernel<<<N_TOKENS / MT, 256, 0, stream>>>(x, cb, fx2, fc2, fidx);
    vq_gather_kernel<<<N_TOKENS / 4, 256, 0, stream>>>(cb, fidx, out);
  }
}